// Round 1
// baseline (940.895 us; speedup 1.0000x reference)
//
#include <hip/hip_runtime.h>
#include <math.h>

// Problem constants
#define N_ROWS 16384
#define VOCAB  8192
#define EMB    256

// Tiling for the fp32 dist/argmin kernel
#define BN 128          // z rows per block
#define BV 128          // codebook rows per v-tile
#define BK 32           // K chunk staged in LDS
#define VSPLIT 4        // blocks splitting the V dimension
#define VRANGE (VOCAB / VSPLIT)   // 2048
#define NVT    (VRANGE / BV)      // 16 v-tiles per block

// ---------------------------------------------------------------------------
// Kernel 1: e_sq[v] = ||codebook[v]||^2. One wave (64 lanes) per row.
// ---------------------------------------------------------------------------
__global__ void esq_kernel(const float* __restrict__ cb, float* __restrict__ esq) {
    const int wave = threadIdx.x >> 6;      // 0..3
    const int lane = threadIdx.x & 63;
    const int row  = blockIdx.x * 4 + wave;
    const float4 v = *(const float4*)(cb + row * EMB + lane * 4);
    float s = v.x * v.x + v.y * v.y + v.z * v.z + v.w * v.w;
    #pragma unroll
    for (int off = 32; off > 0; off >>= 1) s += __shfl_down(s, off, 64);
    if (lane == 0) esq[row] = s;
}

// ---------------------------------------------------------------------------
// Kernel 2: tiled fp32 distance + running argmin.
// dist'(n,v) = e_sq[v] - 2*dot(z_n, e_v)   (z_sq dropped: constant per row)
// Block: 256 threads, computes BN x BV accumulator tile per v-tile.
// Wave-internal 8x8 lane layout -> both LDS fragment reads are
// broadcast-heavy b128 (2-way bank aliasing only).
// Partial (dist, idx) per row per v-split written to workspace.
// ---------------------------------------------------------------------------
__global__ __launch_bounds__(256, 2)
void dist_argmin_kernel(const float* __restrict__ z,
                        const float* __restrict__ cb,
                        const float* __restrict__ esq,
                        float* __restrict__ pdist,
                        int*   __restrict__ pidx) {
    __shared__ float zs[BK][BN + 4];   // transposed: zs[k][n], row 132 floats (16B-aligned rows)
    __shared__ float es[BK][BV + 4];   // transposed: es[k][v]
    __shared__ float rdist[16][16];    // [rowGroup][colGroup] reduction scratch
    __shared__ int   ridx [16][16];

    const int bn    = blockIdx.x;           // 0..127
    const int vs    = blockIdx.y;           // 0..VSPLIT-1
    const int row0  = bn * BN;
    const int vbase = vs * VRANGE;

    const int tid  = threadIdx.x;
    const int wave = tid >> 6;              // 0..3
    const int lane = tid & 63;
    const int wly  = (lane >> 3) & 7;       // wave-local row group 0..7
    const int wlx  = lane & 7;              // wave-local col group 0..7

    // fragment origins: waves 0,1 -> rows 0..63; waves 2,3 -> rows 64..127
    //                   waves 0,2 -> cols 0..63; waves 1,3 -> cols 64..127
    const int rfrag = (wave >> 1) * 64 + wly * 8;   // local row base (8 rows)
    const int cfrag = (wave & 1) * 64 + wlx * 8;    // local col base (8 cols)
    const int rowGroup = (wave >> 1) * 8 + wly;     // 0..15  (= rfrag/8)
    const int colGroup = (wave & 1) * 8 + wlx;      // 0..15  (= cfrag/8)

    float best[8];
    int   bidx[8];
    #pragma unroll
    for (int i = 0; i < 8; ++i) { best[i] = INFINITY; bidx[i] = 0; }

    for (int vt = 0; vt < NVT; ++vt) {
        const int v0 = vbase + vt * BV;

        float acc[8][8];
        #pragma unroll
        for (int i = 0; i < 8; ++i)
            #pragma unroll
            for (int j = 0; j < 8; ++j) acc[i][j] = 0.0f;

        for (int kt = 0; kt < EMB / BK; ++kt) {
            // Stage A (z) and B (codebook) tiles into LDS, transposed to [k][row].
            // 128 rows x 32 cols = 1024 float4 per tile; 4 float4 per thread per tile.
            #pragma unroll
            for (int t = 0; t < 4; ++t) {
                const int vecIdx = tid + t * 256;   // 0..1023
                const int r  = vecIdx >> 3;         // 0..127
                const int c4 = vecIdx & 7;          // float4 index within 32-col chunk
                const float4 va = *(const float4*)(z  + (size_t)(row0 + r) * EMB + kt * BK + c4 * 4);
                zs[c4 * 4 + 0][r] = va.x;
                zs[c4 * 4 + 1][r] = va.y;
                zs[c4 * 4 + 2][r] = va.z;
                zs[c4 * 4 + 3][r] = va.w;
                const float4 vb = *(const float4*)(cb + (size_t)(v0 + r) * EMB + kt * BK + c4 * 4);
                es[c4 * 4 + 0][r] = vb.x;
                es[c4 * 4 + 1][r] = vb.y;
                es[c4 * 4 + 2][r] = vb.z;
                es[c4 * 4 + 3][r] = vb.w;
            }
            __syncthreads();

            #pragma unroll 4
            for (int k = 0; k < BK; ++k) {
                const float4 a0 = *(const float4*)&zs[k][rfrag];
                const float4 a1 = *(const float4*)&zs[k][rfrag + 4];
                const float4 b0 = *(const float4*)&es[k][cfrag];
                const float4 b1 = *(const float4*)&es[k][cfrag + 4];
                const float a[8] = {a0.x, a0.y, a0.z, a0.w, a1.x, a1.y, a1.z, a1.w};
                const float b[8] = {b0.x, b0.y, b0.z, b0.w, b1.x, b1.y, b1.z, b1.w};
                #pragma unroll
                for (int i = 0; i < 8; ++i)
                    #pragma unroll
                    for (int j = 0; j < 8; ++j)
                        acc[i][j] += a[i] * b[j];   // contracts to v_fma_f32
            }
            __syncthreads();
        }

        // Epilogue for this v-tile: dist' = e_sq[v] - 2*acc; running argmin.
        // j ascending + vt ascending => strict '<' keeps the lowest tied index.
        #pragma unroll
        for (int j = 0; j < 8; ++j) {
            const int v = v0 + cfrag + j;
            const float ev = esq[v];
            #pragma unroll
            for (int i = 0; i < 8; ++i) {
                const float d = ev - 2.0f * acc[i][j];
                if (d < best[i]) { best[i] = d; bidx[i] = v; }
            }
        }
    }

    // Cross-thread argmin over the 16 column groups sharing each row.
    for (int i = 0; i < 8; ++i) {
        rdist[rowGroup][colGroup] = best[i];
        ridx [rowGroup][colGroup] = bidx[i];
        __syncthreads();
        if (colGroup == 0) {
            float bd = rdist[rowGroup][0];
            int   bi = ridx [rowGroup][0];
            #pragma unroll
            for (int t = 1; t < 16; ++t) {
                const float d  = rdist[rowGroup][t];
                const int   ii = ridx [rowGroup][t];
                if (d < bd || (d == bd && ii < bi)) { bd = d; bi = ii; }
            }
            const int row = row0 + rowGroup * 8 + i;
            pdist[(size_t)vs * N_ROWS + row] = bd;
            pidx [(size_t)vs * N_ROWS + row] = bi;
        }
        __syncthreads();
    }
}

// ---------------------------------------------------------------------------
// Kernel 3: merge VSPLIT partials per row; emit token (as float), gather z_q,
// histogram via atomicAdd. One wave per row.
// ---------------------------------------------------------------------------
__global__ void combine_kernel(const float* __restrict__ pdist,
                               const int*   __restrict__ pidx,
                               const float* __restrict__ cb,
                               float* __restrict__ tokens,
                               float* __restrict__ zq,
                               float* __restrict__ cnt) {
    const int wave = threadIdx.x >> 6;
    const int lane = threadIdx.x & 63;
    const int row  = blockIdx.x * 4 + wave;

    float bd = INFINITY;
    int   bi = 0;
    #pragma unroll
    for (int s = 0; s < VSPLIT; ++s) {
        const float d  = pdist[(size_t)s * N_ROWS + row];
        const int   ii = pidx [(size_t)s * N_ROWS + row];
        if (d < bd || (d == bd && ii < bi)) { bd = d; bi = ii; }
    }
    if (lane == 0) {
        tokens[row] = (float)bi;                 // token index, exact in fp32 (< 2^24)
        atomicAdd(&cnt[bi], 1.0f);
    }
    const float4 v = *(const float4*)(cb + (size_t)bi * EMB + lane * 4);
    *(float4*)(zq + (size_t)row * EMB + lane * 4) = v;
}

// ---------------------------------------------------------------------------
// Launch. d_out layout (float32, reference return order):
//   [0, N)              tokens (as float)
//   [N, N + N*EMB)      z_q
//   [N + N*EMB, +VOCAB) ref_count
// Workspace: e_sq (VOCAB f32) | pdist (VSPLIT*N f32) | pidx (VSPLIT*N i32)
//   = 32 KB + 256 KB + 256 KB = 544 KB.
// ---------------------------------------------------------------------------
extern "C" void kernel_launch(void* const* d_in, const int* in_sizes, int n_in,
                              void* d_out, int out_size, void* d_ws, size_t ws_size,
                              hipStream_t stream) {
    const float* z  = (const float*)d_in[0];
    const float* cb = (const float*)d_in[1];

    float* out    = (float*)d_out;
    float* tokens = out;
    float* zq     = out + N_ROWS;
    float* cnt    = out + N_ROWS + (size_t)N_ROWS * EMB;

    float* esq   = (float*)d_ws;
    float* pdist = esq + VOCAB;
    int*   pidx  = (int*)(pdist + (size_t)VSPLIT * N_ROWS);

    // histogram needs zeros (d_out is poisoned 0xAA before every launch)
    hipMemsetAsync(cnt, 0, VOCAB * sizeof(float), stream);

    esq_kernel<<<VOCAB / 4, 256, 0, stream>>>(cb, esq);
    dist_argmin_kernel<<<dim3(N_ROWS / BN, VSPLIT), 256, 0, stream>>>(z, cb, esq, pdist, pidx);
    combine_kernel<<<N_ROWS / 4, 256, 0, stream>>>(pdist, pidx, cb, tokens, zq, cnt);
}